// Round 3
// baseline (191.985 us; speedup 1.0000x reference)
//
#include <hip/hip_runtime.h>

#define HIDDEN 128
#define BSHIFT 10           // dst bucket = dst >> 10
#define NBMAX 128           // >= 98 buckets
#define CAP 10752           // slots/bucket: mean 10240, sigma ~101 -> +5 sigma; %32==0
#define OVF_MAX 65536

typedef _Float16 f16;
typedef f16 f16x2 __attribute__((ext_vector_type(2)));
typedef f16 f16x4 __attribute__((ext_vector_type(4)));
typedef f16 f16x8 __attribute__((ext_vector_type(8)));
typedef float f32x16 __attribute__((ext_vector_type(16)));
typedef unsigned long long ull;
typedef ull ull2 __attribute__((ext_vector_type(2)));

static __device__ __forceinline__ float fdot2(f16x2 a, f16x2 b, float c) {
    return __builtin_amdgcn_fdot2(a, b, c, false);   // v_dot2_f32_f16
}

// Unified front end: blocks [0,nscat) = counting scatter; blocks [nscat,...) = MFMA gemm.
// prep_w eliminated: each gemm block builds Wsym^T (XOR-swizzled, 32KB LDS) from w directly;
// cursor is delta-based (zeroed by a 528B hipMemsetAsync before launch).
// perm entry: src | dst<<17 | (eid+1)<<34  (eid+1 so zero slack slots never store)
__global__ __launch_bounds__(256) void gemm_scatter(const float* __restrict__ z,
                                                    const float* __restrict__ w,
                                                    f16* __restrict__ zh,
                                                    f16* __restrict__ uh,
                                                    const int* __restrict__ eidx,
                                                    int* __restrict__ cursor,
                                                    ull* __restrict__ perm,
                                                    ull* __restrict__ ovf,
                                                    int* __restrict__ ovf_cnt,
                                                    int nrows, int E, int nb, int nscat) {
    __shared__ f16 wlt[HIDDEN * HIDDEN];   // 32768 B exactly -> 5 blocks/CU LDS-ceiling
    int tid = threadIdx.x;

    if (blockIdx.x < nscat) {
        // ---- scatter path (overlays 1.5 KB of wlt) ----
        int* lh    = (int*)wlt;
        int* lbase = lh + NBMAX;
        int* lrank = lbase + NBMAX;
        int base = blockIdx.x * 4096;
        if (tid < NBMAX) { lh[tid] = 0; lrank[tid] = 0; }
        __syncthreads();
        int s[16], d[16], bb[16];
        #pragma unroll
        for (int i = 0; i < 16; ++i) {
            int e = base + i * 256 + tid;
            bb[i] = -1;
            if (e < E) {
                s[i] = eidx[e]; d[i] = eidx[E + e];
                bb[i] = d[i] >> BSHIFT;
                atomicAdd(&lh[bb[i]], 1);
            }
        }
        __syncthreads();
        if (tid < nb && lh[tid]) lbase[tid] = atomicAdd(&cursor[tid], lh[tid]);  // delta base
        __syncthreads();
        #pragma unroll
        for (int i = 0; i < 16; ++i) {
            if (bb[i] >= 0) {
                int e = base + i * 256 + tid;
                int r = atomicAdd(&lrank[bb[i]], 1);
                int pib = lbase[bb[i]] + r;              // position within bucket
                ull v = (ull)s[i] | ((ull)d[i] << 17) | ((ull)(e + 1) << 34);
                if (pib < CAP) perm[(long)bb[i] * CAP + pib] = v;
                else {                                   // statistically ~never
                    int o = atomicAdd(ovf_cnt, 1);
                    if (o < OVF_MAX) ovf[o] = v;
                }
            }
        }
        return;
    }

    // ---- gemm path: uh = (f16)(z @ Wsym), zh = (f16)z fused ----
    {   // build Wsym^T in LDS from w: wlt[n][k ^ ((n&7)<<3)] = w[k][n] + w[n][k]
        #pragma unroll
        for (int it = 0; it < 16; ++it) {
            int idx4 = (it * 256 + tid) * 4;            // 0..16380
            int n = idx4 >> 7, k0 = idx4 & 127;
            float4 wr = *(const float4*)&w[n * HIDDEN + k0];      // coalesced
            float c0 = w[(k0 + 0) * HIDDEN + n];                  // transposed gathers (L1/L2-hot)
            float c1 = w[(k0 + 1) * HIDDEN + n];
            float c2 = w[(k0 + 2) * HIDDEN + n];
            float c3 = w[(k0 + 3) * HIDDEN + n];
            f16x4 v = {(f16)(wr.x + c0), (f16)(wr.y + c1), (f16)(wr.z + c2), (f16)(wr.w + c3)};
            *(f16x4*)&wlt[n * HIDDEN + (k0 ^ ((n & 7) << 3))] = v;   // 8B store, swizzle-consistent
        }
    }
    __syncthreads();

    int wave = tid >> 6, lane = tid & 63;
    int tile = blockIdx.x - nscat;
    int row0 = tile * 128 + wave * 32;
    if (row0 > nrows - 32) row0 = nrows - 32;   // tail overlap: identical writes, benign

    int m = lane & 31, half = lane >> 5;        // A: row=m, k=half*8+j
    int swz = (m & 7) << 3;                     // XOR swizzle (halves), same for rows m+32k
    const float* zr = z  + (size_t)(row0 + m) * HIDDEN + half * 8;
    f16*        zhr = zh + (size_t)(row0 + m) * HIDDEN + half * 8;
    const f16* wrow = &wlt[m * HIDDEN];

    f32x16 acc0, acc1, acc2, acc3;
    #pragma unroll
    for (int r = 0; r < 16; ++r) { acc0[r] = 0.f; acc1[r] = 0.f; acc2[r] = 0.f; acc3[r] = 0.f; }

    #pragma unroll
    for (int ks = 0; ks < 8; ++ks) {            // K = 16 per step
        float4 a0 = *(const float4*)(zr + 16 * ks);
        float4 a1 = *(const float4*)(zr + 16 * ks + 4);
        f16x8 af = {(f16)a0.x, (f16)a0.y, (f16)a0.z, (f16)a0.w,
                    (f16)a1.x, (f16)a1.y, (f16)a1.z, (f16)a1.w};
        *(f16x8*)(zhr + 16 * ks) = af;          // fused zh emit
        int c = (half * 8 + 16 * ks) ^ swz;     // 16B-aligned (swz multiple of 8 halves)
        f16x8 b0 = *(const f16x8*)&wrow[c];
        f16x8 b1 = *(const f16x8*)&wrow[32 * HIDDEN + c];
        f16x8 b2 = *(const f16x8*)&wrow[64 * HIDDEN + c];
        f16x8 b3 = *(const f16x8*)&wrow[96 * HIDDEN + c];
        acc0 = __builtin_amdgcn_mfma_f32_32x32x16_f16(af, b0, acc0, 0, 0, 0);
        acc1 = __builtin_amdgcn_mfma_f32_32x32x16_f16(af, b1, acc1, 0, 0, 0);
        acc2 = __builtin_amdgcn_mfma_f32_32x32x16_f16(af, b2, acc2, 0, 0, 0);
        acc3 = __builtin_amdgcn_mfma_f32_32x32x16_f16(af, b3, acc3, 0, 0, 0);
    }

    // C/D: col = m (+32/tile), row = (r&3) + 8*(r>>2) + 4*half   [m74/m101]
    f16* ur = uh + (size_t)row0 * HIDDEN;
    #pragma unroll
    for (int r = 0; r < 16; ++r) {
        int row = (r & 3) + 8 * (r >> 2) + 4 * half;
        f16* p = ur + (size_t)row * HIDDEN + m;
        p[0]  = (f16)acc0[r];
        p[32] = (f16)acc1[r];
        p[64] = (f16)acc2[r];
        p[96] = (f16)acc3[r];
    }
}

// Single-edge scorer (overflow tail + fallback path). eid field is eid+1; 0 = no store.
static __device__ __forceinline__ void score_edge(const f16* uh, const f16* zh,
                                                  ull p, float* out, int t, int E) {
    int src = (int)(p & 0x1FFFF);
    int dst = (int)((p >> 17) & 0x1FFFF);
    int ep  = (int)(p >> 34);
    const float4* a4 = (const float4*)(uh + (size_t)src * HIDDEN);
    const float4* b4 = (const float4*)(zh + (size_t)dst * HIDDEN);
    float4 av = a4[t], bv = b4[t];   // plain loads: src reuse (~10x) wants caching
    const f16x2* ap = (const f16x2*)&av;
    const f16x2* bp = (const f16x2*)&bv;
    float s = 0.f;
    #pragma unroll
    for (int i = 0; i < 4; ++i) s = fdot2(ap[i], bp[i], s);
    #pragma unroll
    for (int off = 8; off > 0; off >>= 1) s += __shfl_down(s, off, 16);
    if (t == 0 && ep > 0 && ep <= E) out[ep - 1] = 1.0f / (1.0f + __expf(-s));
}

// Binned scoring over slotted perm (XCD-swizzled) + overflow tail blocks fused.
// R1 2-edge body (best measured: 48.6 us; 4-edge regressed -> memory path saturated).
__global__ __launch_bounds__(256, 8) void edge_bin(const f16* __restrict__ uh,
                                                   const f16* __restrict__ zh,
                                                   const ull* __restrict__ perm,
                                                   const ull* __restrict__ ovf,
                                                   const int* __restrict__ ovf_cnt,
                                                   float* __restrict__ out,
                                                   int E, int cpx, int nmain) {
    int tid = threadIdx.x;
    int g = tid >> 4, t = tid & 15;
    int b = blockIdx.x;
    if (b >= nmain) {                         // overflow tail (statistically empty)
        int n = ovf_cnt[0];
        if (n > OVF_MAX) n = OVF_MAX;
        for (int i = (b - nmain) * 16 + g; i < n; i += 32 * 16)
            score_edge(uh, zh, ovf[i], out, t, E);
        return;
    }
    int chunk = (b & 7) * cpx + (b >> 3);     // XCD b%8 -> contiguous dst slice (L2-fit)
    long slot = (long)chunk * 32 + g * 2;     // 32 slots/block, 2 per group, contiguous
    ull2 p = *(const ull2*)&perm[slot];       // 16B aligned

    int src0 = (int)(p.x & 0x1FFFF), dst0 = (int)((p.x >> 17) & 0x1FFFF), e0 = (int)(p.x >> 34);
    int src1 = (int)(p.y & 0x1FFFF), dst1 = (int)((p.y >> 17) & 0x1FFFF), e1 = (int)(p.y >> 34);

    // issue all 4 row gathers before any dependent math
    float4 a0 = ((const float4*)(uh + (size_t)src0 * HIDDEN))[t];
    float4 b0 = ((const float4*)(zh + (size_t)dst0 * HIDDEN))[t];
    float4 a1 = ((const float4*)(uh + (size_t)src1 * HIDDEN))[t];
    float4 b1 = ((const float4*)(zh + (size_t)dst1 * HIDDEN))[t];

    const f16x2* ap0 = (const f16x2*)&a0; const f16x2* bp0 = (const f16x2*)&b0;
    const f16x2* ap1 = (const f16x2*)&a1; const f16x2* bp1 = (const f16x2*)&b1;
    float s0 = 0.f, s1 = 0.f;
    #pragma unroll
    for (int i = 0; i < 4; ++i) {
        s0 = fdot2(ap0[i], bp0[i], s0);
        s1 = fdot2(ap1[i], bp1[i], s1);
    }
    #pragma unroll
    for (int off = 8; off > 0; off >>= 1) {   // independent butterfly chains
        s0 += __shfl_xor(s0, off, 16);
        s1 += __shfl_xor(s1, off, 16);
    }
    float sv = (t == 0) ? s0 : s1;
    int   ev = (t == 0) ? e0 : e1;
    if (t < 2 && ev > 0 && ev <= E) out[ev - 1] = 1.0f / (1.0f + __expf(-sv));
}

// fallback (R5 path) if workspace too small for the binned layout
__global__ __launch_bounds__(256) void edge_score16(const f16* __restrict__ uh,
                                                    const f16* __restrict__ zh,
                                                    const int* __restrict__ eidx,
                                                    float* __restrict__ out, int E) {
    int tid = threadIdx.x;
    int g = tid >> 4, t = tid & 15;
    int e = blockIdx.x * 16 + g;
    if (e >= E) return;
    ull p = (ull)eidx[e] | ((ull)eidx[E + e] << 17) | ((ull)(e + 1) << 34);
    score_edge(uh, zh, p, out, t, E);
}

extern "C" void kernel_launch(void* const* d_in, const int* in_sizes, int n_in,
                              void* d_out, int out_size, void* d_ws, size_t ws_size,
                              hipStream_t stream) {
    const float* z    = (const float*)d_in[0];
    const int*   eidx = (const int*)d_in[1];
    const float* w    = (const float*)d_in[2];
    float* out = (float*)d_out;

    int nrows = in_sizes[0] / HIDDEN;   // 100000
    int E = out_size;                    // 1000000
    int nb = (nrows >> BSHIFT) + 1;      // 98

    f16* zh     = (f16*)d_ws;                               // 25.6 MB
    f16* uh     = zh + (size_t)nrows * HIDDEN;              // 25.6 MB
    int* cursor = (int*)(uh + (size_t)nrows * HIDDEN);      // 128 ints (deltas, zero-init)
    int* ovf_cnt = cursor + NBMAX;                          // 4 ints (pad keeps 16B alignment)
    ull* ovf    = (ull*)(ovf_cnt + 4);                      // 512 KB
    ull* perm   = ovf + OVF_MAX;                            // nb*CAP slots (~8.4 MB), 16B aligned

    long nslots = (long)nb * CAP;
    size_t need = (size_t)((char*)(perm + nslots) - (char*)d_ws);
    bool binned = ws_size >= need;       // ws_size fixed per session -> same path every call

    int ngemm = (nrows + 127) / 128;     // 782
    int nscat = (E + 4095) / 4096;       // 245

    // zero cursor deltas + ovf_cnt (528 B memset node; replaces the prep_w dispatch)
    hipMemsetAsync(cursor, 0, (NBMAX + 4) * sizeof(int), stream);

    if (binned) {
        gemm_scatter<<<nscat + ngemm, 256, 0, stream>>>(z, w, zh, uh, eidx, cursor,
                                                        perm, ovf, ovf_cnt, nrows, E, nb, nscat);
        long ngrp = nslots / 32;          // CAP%32==0 -> exact; 98*10752/32 = 32928, %8==0
        int cpx = (int)(ngrp / 8);
        int nmain = (int)ngrp;
        edge_bin<<<nmain + 32, 256, 0, stream>>>(uh, zh, perm, ovf, ovf_cnt, out, E, cpx, nmain);
    } else {
        gemm_scatter<<<ngemm, 256, 0, stream>>>(z, w, zh, uh, eidx, cursor,
                                                perm, ovf, ovf_cnt, nrows, E, nb, 0);
        edge_score16<<<(E + 15) / 16, 256, 0, stream>>>(uh, zh, eidx, out, E);
    }
}

// Round 5
// 157.052 us; speedup vs baseline: 1.2224x; 1.2224x over previous
//
#include <hip/hip_runtime.h>

#define HIDDEN 128
#define BSHIFT 10           // dst bucket = dst >> 10
#define NBMAX 128           // >= 98 buckets
#define CAP 10752           // slots/bucket: mean 10240, sigma ~101 -> +5 sigma; %32==0
#define OVF_MAX 65536

typedef _Float16 f16;
typedef f16 f16x2 __attribute__((ext_vector_type(2)));
typedef f16 f16x8 __attribute__((ext_vector_type(8)));
typedef float f32x16 __attribute__((ext_vector_type(16)));
typedef unsigned long long ull;
typedef ull ull2 __attribute__((ext_vector_type(2)));

static __device__ __forceinline__ float fdot2(f16x2 a, f16x2 b, float c) {
    return __builtin_amdgcn_fdot2(a, b, c, false);   // v_dot2_f32_f16
}

// wsh_t[n][k] = Wsym[k][n] (fp16, B-operand layout, LINEAR); init cursor[b]=b*CAP, ovf_cnt=0
__global__ __launch_bounds__(256) void prep_w(const float* __restrict__ w,
                                              f16* __restrict__ wsh_t,
                                              int* __restrict__ cursor,
                                              int* __restrict__ ovf_cnt) {
    int idx = blockIdx.x * 256 + threadIdx.x;   // 0..16383
    if (idx < NBMAX) cursor[idx] = idx * CAP;
    if (idx == NBMAX) ovf_cnt[0] = 0;
    int n = idx >> 7, k = idx & 127;
    wsh_t[idx] = (f16)(w[k * HIDDEN + n] + w[n * HIDDEN + k]);
}

// Fused launch: blocks [0,ngemm) = MFMA gemm tiles; blocks [ngemm,...) = counting scatter.
// R4: W tile in LDS is 32768 B exactly (5 blocks/CU; grid 1027 <= 1280 capacity -> no
// straggler round) via GRANULE ROTATION: 16B granule g of row j stored at granule
// (g+(j&7))&15. Bank-derivation: row stride 64 dwords == 0 mod 32 banks, so banks depend
// only on granule index; over 64 lanes each bank gets exactly 8 accesses per b128 = HW
// minimum -> 0 conflicts (same as the old LDSW=136 pad, 2.5KB smaller).
// perm entry: src | dst<<17 | (eid+1)<<34  (eid+1 so zero slack slots never store)
__global__ __launch_bounds__(256) void gemm_scatter(const float* __restrict__ z,
                                                    const f16* __restrict__ wsh_t,
                                                    f16* __restrict__ zh,
                                                    f16* __restrict__ uh,
                                                    const int* __restrict__ eidx,
                                                    int* __restrict__ cursor,
                                                    ull* __restrict__ perm,
                                                    ull* __restrict__ ovf,
                                                    int* __restrict__ ovf_cnt,
                                                    int nrows, int E, int nb, int ngemm) {
    __shared__ f16 wlt[HIDDEN * HIDDEN];   // 32768 B exactly
    int tid = threadIdx.x;

    if (blockIdx.x >= ngemm) {
        // ---- scatter path (overlays 1.5 KB of wlt) ----
        int* lh    = (int*)wlt;
        int* lbase = lh + NBMAX;
        int* lrank = lbase + NBMAX;
        int base = (blockIdx.x - ngemm) * 4096;
        if (tid < NBMAX) { lh[tid] = 0; lrank[tid] = 0; }
        __syncthreads();
        int s[16], d[16], bb[16];
        #pragma unroll
        for (int i = 0; i < 16; ++i) {
            int e = base + i * 256 + tid;
            bb[i] = -1;
            if (e < E) {
                s[i] = eidx[e]; d[i] = eidx[E + e];
                bb[i] = d[i] >> BSHIFT;
                atomicAdd(&lh[bb[i]], 1);
            }
        }
        __syncthreads();
        if (tid < nb && lh[tid]) lbase[tid] = atomicAdd(&cursor[tid], lh[tid]);
        __syncthreads();
        #pragma unroll
        for (int i = 0; i < 16; ++i) {
            if (bb[i] >= 0) {
                int e = base + i * 256 + tid;
                int r = atomicAdd(&lrank[bb[i]], 1);
                long pos = (long)lbase[bb[i]] + r;
                ull v = (ull)s[i] | ((ull)d[i] << 17) | ((ull)(e + 1) << 34);
                if (pos < (long)(bb[i] + 1) * CAP) perm[pos] = v;
                else {                                   // statistically ~never
                    int o = atomicAdd(ovf_cnt, 1);
                    if (o < OVF_MAX) ovf[o] = v;
                }
            }
        }
        return;
    }

    // ---- gemm path: uh = (f16)(z @ Wsym), zh = (f16)z fused ----
    {   // stage W^T: linear global granule (j,kc) -> LDS granule (j, (kc+(j&7))&15)
        const f16x8* g = (const f16x8*)wsh_t;
        #pragma unroll
        for (int it = 0; it < 8; ++it) {
            int idx = it * 256 + tid;                   // 0..2047
            int j = idx >> 4, kc = idx & 15;
            *(f16x8*)&wlt[j * HIDDEN + (((kc + (j & 7)) & 15) << 3)] = g[idx];
        }
    }
    __syncthreads();

    int wave = tid >> 6, lane = tid & 63;
    int row0 = blockIdx.x * 128 + wave * 32;
    if (row0 > nrows - 32) row0 = nrows - 32;   // tail overlap: identical writes, benign

    int m = lane & 31, half = lane >> 5;        // A: row=m, k=half*8+j
    int rot = m & 7;                            // same for rows m+32k -> one rot for all 4 B-frags
    const float* zr = z  + (size_t)(row0 + m) * HIDDEN + half * 8;
    f16*        zhr = zh + (size_t)(row0 + m) * HIDDEN + half * 8;
    const f16* wrow = &wlt[m * HIDDEN];

    f32x16 acc0, acc1, acc2, acc3;
    #pragma unroll
    for (int r = 0; r < 16; ++r) { acc0[r] = 0.f; acc1[r] = 0.f; acc2[r] = 0.f; acc3[r] = 0.f; }

    #pragma unroll
    for (int ks = 0; ks < 8; ++ks) {            // K = 16 per step
        float4 a0 = *(const float4*)(zr + 16 * ks);
        float4 a1 = *(const float4*)(zr + 16 * ks + 4);
        f16x8 af = {(f16)a0.x, (f16)a0.y, (f16)a0.z, (f16)a0.w,
                    (f16)a1.x, (f16)a1.y, (f16)a1.z, (f16)a1.w};
        *(f16x8*)(zhr + 16 * ks) = af;          // fused zh emit
        int c = ((half + 2 * ks + rot) & 15) << 3;   // rotated granule of linear (half*8+16ks)
        f16x8 b0 = *(const f16x8*)&wrow[c];
        f16x8 b1 = *(const f16x8*)&wrow[32 * HIDDEN + c];
        f16x8 b2 = *(const f16x8*)&wrow[64 * HIDDEN + c];
        f16x8 b3 = *(const f16x8*)&wrow[96 * HIDDEN + c];
        acc0 = __builtin_amdgcn_mfma_f32_32x32x16_f16(af, b0, acc0, 0, 0, 0);
        acc1 = __builtin_amdgcn_mfma_f32_32x32x16_f16(af, b1, acc1, 0, 0, 0);
        acc2 = __builtin_amdgcn_mfma_f32_32x32x16_f16(af, b2, acc2, 0, 0, 0);
        acc3 = __builtin_amdgcn_mfma_f32_32x32x16_f16(af, b3, acc3, 0, 0, 0);
    }

    // C/D: col = m (+32/tile), row = (r&3) + 8*(r>>2) + 4*half   [m74/m101]
    f16* ur = uh + (size_t)row0 * HIDDEN;
    #pragma unroll
    for (int r = 0; r < 16; ++r) {
        int row = (r & 3) + 8 * (r >> 2) + 4 * half;
        f16* p = ur + (size_t)row * HIDDEN + m;
        p[0]  = (f16)acc0[r];
        p[32] = (f16)acc1[r];
        p[64] = (f16)acc2[r];
        p[96] = (f16)acc3[r];
    }
}

// Single-edge scorer (overflow tail + fallback path). eid field is eid+1; 0 = no store.
static __device__ __forceinline__ void score_edge(const f16* uh, const f16* zh,
                                                  ull p, float* out, int t, int E) {
    int src = (int)(p & 0x1FFFF);
    int dst = (int)((p >> 17) & 0x1FFFF);
    int ep  = (int)(p >> 34);
    const float4* a4 = (const float4*)(uh + (size_t)src * HIDDEN);
    const float4* b4 = (const float4*)(zh + (size_t)dst * HIDDEN);
    float4 av = a4[t], bv = b4[t];   // plain loads: src reuse (~10x) wants caching
    const f16x2* ap = (const f16x2*)&av;
    const f16x2* bp = (const f16x2*)&bv;
    float s = 0.f;
    #pragma unroll
    for (int i = 0; i < 4; ++i) s = fdot2(ap[i], bp[i], s);
    #pragma unroll
    for (int off = 8; off > 0; off >>= 1) s += __shfl_down(s, off, 16);
    if (t == 0 && ep > 0 && ep <= E) out[ep - 1] = 1.0f / (1.0f + __expf(-s));
}

// Binned scoring over slotted perm (XCD-swizzled) + overflow tail blocks fused.
// R1 2-edge body (best measured: 48.6 us; 4-edge regressed -> gather path saturated).
__global__ __launch_bounds__(256, 8) void edge_bin(const f16* __restrict__ uh,
                                                   const f16* __restrict__ zh,
                                                   const ull* __restrict__ perm,
                                                   const ull* __restrict__ ovf,
                                                   const int* __restrict__ ovf_cnt,
                                                   float* __restrict__ out,
                                                   int E, int cpx, int nmain) {
    int tid = threadIdx.x;
    int g = tid >> 4, t = tid & 15;
    int b = blockIdx.x;
    if (b >= nmain) {                         // overflow tail (statistically empty)
        int n = ovf_cnt[0];
        if (n > OVF_MAX) n = OVF_MAX;
        for (int i = (b - nmain) * 16 + g; i < n; i += 32 * 16)
            score_edge(uh, zh, ovf[i], out, t, E);
        return;
    }
    int chunk = (b & 7) * cpx + (b >> 3);     // XCD b%8 -> contiguous dst slice (L2-fit)
    long slot = (long)chunk * 32 + g * 2;     // 32 slots/block, 2 per group, contiguous
    ull2 p = *(const ull2*)&perm[slot];       // 16B aligned

    int src0 = (int)(p.x & 0x1FFFF), dst0 = (int)((p.x >> 17) & 0x1FFFF), e0 = (int)(p.x >> 34);
    int src1 = (int)(p.y & 0x1FFFF), dst1 = (int)((p.y >> 17) & 0x1FFFF), e1 = (int)(p.y >> 34);

    // issue all 4 row gathers before any dependent math
    float4 a0 = ((const float4*)(uh + (size_t)src0 * HIDDEN))[t];
    float4 b0 = ((const float4*)(zh + (size_t)dst0 * HIDDEN))[t];
    float4 a1 = ((const float4*)(uh + (size_t)src1 * HIDDEN))[t];
    float4 b1 = ((const float4*)(zh + (size_t)dst1 * HIDDEN))[t];

    const f16x2* ap0 = (const f16x2*)&a0; const f16x2* bp0 = (const f16x2*)&b0;
    const f16x2* ap1 = (const f16x2*)&a1; const f16x2* bp1 = (const f16x2*)&b1;
    float s0 = 0.f, s1 = 0.f;
    #pragma unroll
    for (int i = 0; i < 4; ++i) {
        s0 = fdot2(ap0[i], bp0[i], s0);
        s1 = fdot2(ap1[i], bp1[i], s1);
    }
    #pragma unroll
    for (int off = 8; off > 0; off >>= 1) {   // independent butterfly chains
        s0 += __shfl_xor(s0, off, 16);
        s1 += __shfl_xor(s1, off, 16);
    }
    float sv = (t == 0) ? s0 : s1;
    int   ev = (t == 0) ? e0 : e1;
    if (t < 2 && ev > 0 && ev <= E) out[ev - 1] = 1.0f / (1.0f + __expf(-sv));
}

// fallback (R5 path) if workspace too small for the binned layout
__global__ __launch_bounds__(256) void edge_score16(const f16* __restrict__ uh,
                                                    const f16* __restrict__ zh,
                                                    const int* __restrict__ eidx,
                                                    float* __restrict__ out, int E) {
    int tid = threadIdx.x;
    int g = tid >> 4, t = tid & 15;
    int e = blockIdx.x * 16 + g;
    if (e >= E) return;
    ull p = (ull)eidx[e] | ((ull)eidx[E + e] << 17) | ((ull)(e + 1) << 34);
    score_edge(uh, zh, p, out, t, E);
}

extern "C" void kernel_launch(void* const* d_in, const int* in_sizes, int n_in,
                              void* d_out, int out_size, void* d_ws, size_t ws_size,
                              hipStream_t stream) {
    const float* z    = (const float*)d_in[0];
    const int*   eidx = (const int*)d_in[1];
    const float* w    = (const float*)d_in[2];
    float* out = (float*)d_out;

    int nrows = in_sizes[0] / HIDDEN;   // 100000
    int E = out_size;                    // 1000000
    int nb = (nrows >> BSHIFT) + 1;      // 98

    f16* wsh_t  = (f16*)d_ws;                               // 32 KB
    f16* zh     = wsh_t + HIDDEN * HIDDEN;                  // 25.6 MB
    f16* uh     = zh + (size_t)nrows * HIDDEN;              // 25.6 MB
    int* cursor = (int*)(uh + (size_t)nrows * HIDDEN);      // NBMAX ints
    int* ovf_cnt = cursor + NBMAX;                          // padded to 16B for perm alignment
    ull* ovf    = (ull*)(ovf_cnt + 4);                      // 512 KB
    ull* perm   = ovf + OVF_MAX;                            // nb*CAP slots (~8.4 MB), 16B aligned

    long nslots = (long)nb * CAP;
    size_t need = (size_t)((char*)(perm + nslots) - (char*)d_ws);
    bool binned = ws_size >= need;       // ws_size fixed per session -> same path every call

    int ngemm = (nrows + 127) / 128;     // 782
    int nscat = (E + 4095) / 4096;       // 245

    prep_w<<<64, 256, 0, stream>>>(w, wsh_t, cursor, ovf_cnt);
    if (binned) {
        gemm_scatter<<<ngemm + nscat, 256, 0, stream>>>(z, wsh_t, zh, uh, eidx, cursor,
                                                        perm, ovf, ovf_cnt, nrows, E, nb, ngemm);
        long ngrp = nslots / 32;          // CAP%32==0 -> exact; 98*10752/32 = 32928, %8==0
        int cpx = (int)(ngrp / 8);
        int nmain = (int)ngrp;
        edge_bin<<<nmain + 32, 256, 0, stream>>>(uh, zh, perm, ovf, ovf_cnt, out, E, cpx, nmain);
    } else {
        gemm_scatter<<<ngemm, 256, 0, stream>>>(z, wsh_t, zh, uh, eidx, cursor,
                                                perm, ovf, ovf_cnt, nrows, E, nb, ngemm);
        edge_score16<<<(E + 15) / 16, 256, 0, stream>>>(uh, zh, eidx, out, E);
    }
}